// Round 7
// baseline (358.747 us; speedup 1.0000x reference)
//
#include <hip/hip_runtime.h>
#include <math.h>

// Problem constants (fixed by the reference)
#define BB 2
#define MM 128
#define NN 128
#define DE 512
#define NH 8
#define DH 64
#define SWIN 8
#define MWIN 16
#define NWIN 16
#define NKEY 116   // 64 + 36 + 16
#define NSLOT 128  // padded to 8 n-tiles of 16

#define NEG_MAX (-3.402823466e38f)
#define LN1E4_OVER_32 0.28782313662425575f   // ln(10000)/32 ; RAD[p] = exp(-p*this)

// level bases in "positions" for the concatenated RK/RV buffers
#define L0_BASE 0       // 2*64*64 = 8192 positions
#define L1_BASE 8192    // 2*32*32 = 2048
#define L2_BASE 10240   // 2*16*16 = 512
#define NPOS_KV 10752

typedef __bf16 bf16_t;
typedef bf16_t bf16x8 __attribute__((ext_vector_type(8)));
typedef bf16_t bf16x4 __attribute__((ext_vector_type(4)));
typedef bf16_t bf16x2 __attribute__((ext_vector_type(2)));
typedef float  f32x4  __attribute__((ext_vector_type(4)));

// async global->LDS, 16B per lane, dest = wave-uniform base + lane*16
#define GLD16(ldsdst, gsrc)                                                  \
    __builtin_amdgcn_global_load_lds(                                        \
        (const __attribute__((address_space(1))) unsigned int*)(gsrc),       \
        (__attribute__((address_space(3))) unsigned int*)(ldsdst), 16, 0, 0)

// ---------------------------------------------------------------------------
// prep: fused fp32->bf16 map conversion (blocks [0,21760)), weight
// transpose+convert (blocks [21760,22016): 4 weights x 64 tiles), and
// RoPE cos/sin table fill (block 22016): tab[pos*16+p] = (cos,sin)(pos*RAD[p])
// for pos 0..127, p 0..15.  Used by rope_kv only (NOT the GEMM epilogues --
// table-in-epilogue measured -50% on gemm_all in round 2: latency-bound
// dependent gathers + register pressure; sincosf there overlaps fine).
// ---------------------------------------------------------------------------
#define CV_S0 16777216
#define CV_S1 20971520
#define CV_S2 22020096
#define CV_S3 22282240
#define CV_BLOCKS 21760
__global__ __launch_bounds__(256) void prep(
    const float* __restrict__ fmap, const float* __restrict__ p0,
    const float* __restrict__ p1, const float* __restrict__ p2,
    const float* __restrict__ Wq, const float* __restrict__ Wk,
    const float* __restrict__ Wv, const float* __restrict__ Wo,
    bf16_t* __restrict__ Afm, bf16_t* __restrict__ Ap0,
    bf16_t* __restrict__ Ap1, bf16_t* __restrict__ Ap2,
    bf16_t* __restrict__ Tq, bf16_t* __restrict__ Tk,
    bf16_t* __restrict__ Tv, bf16_t* __restrict__ To,
    float2* __restrict__ ropetab) {
    __shared__ float Ws[64][65];
    const int bid = blockIdx.x;
    const int tid = threadIdx.x;
    if (bid < CV_BLOCKS) {
        const int e = (bid * 256 + tid) * 4;
        const float* src; bf16_t* dst; int off;
        if (e < CV_S0)      { src = fmap; dst = Afm; off = e; }
        else if (e < CV_S1) { src = p0;   dst = Ap0; off = e - CV_S0; }
        else if (e < CV_S2) { src = p1;   dst = Ap1; off = e - CV_S1; }
        else if (e < CV_S3) { src = p2;   dst = Ap2; off = e - CV_S2; }
        else return;
        const float4 v = *(const float4*)(src + off);
        bf16x4 o;
        o[0] = (bf16_t)v.x; o[1] = (bf16_t)v.y; o[2] = (bf16_t)v.z; o[3] = (bf16_t)v.w;
        *(bf16x4*)(dst + off) = o;
    } else if (bid < CV_BLOCKS + 256) {
        const int idx = bid - CV_BLOCKS;     // 0..255
        const int w = idx >> 6, tile = idx & 63;
        const float* W = (w == 0) ? Wq : (w == 1) ? Wk : (w == 2) ? Wv : Wo;
        bf16_t*      T = (w == 0) ? Tq : (w == 1) ? Tk : (w == 2) ? Tv : To;
        const int tk0 = (tile >> 3) * 64;
        const int tn0 = (tile & 7) * 64;
#pragma unroll 4
        for (int i = 0; i < 16; ++i) {
            const int e = tid + i * 256;
            Ws[e >> 6][e & 63] = W[(tk0 + (e >> 6)) * 512 + tn0 + (e & 63)];
        }
        __syncthreads();
#pragma unroll 4
        for (int i = 0; i < 16; ++i) {
            const int e = tid + i * 256;
            const int ck = e & 63, rn = e >> 6;
            T[(size_t)(tn0 + rn) * 512 + tk0 + ck] = (bf16_t)Ws[ck][rn];
        }
    } else {
        // 2048 entries: tab[pos*16 + p] = (cos(pos*RAD[p]), sin(pos*RAD[p]))
#pragma unroll
        for (int i = 0; i < 8; ++i) {
            const int e = tid * 8 + i;       // 0..2047
            const int posn = e >> 4, p = e & 15;
            const float rad = expf(-LN1E4_OVER_32 * (float)p);
            float sn, cs;
            sincosf((float)posn * rad, &sn, &cs);
            ropetab[e] = make_float2(cs, sn);
        }
    }
}

// ---------------------------------------------------------------------------
// bf16 MFMA GEMM body (128x128 tile, 4 waves, 4x4 16x16x32 frags, BK=64).
// Staging: global_load_lds dwordx4 (async, no VGPR round-trip) into LINEAR
// LDS [128][64], with the XOR bank-swizzle applied on BOTH sides:
//   - SOURCE column pre-swizzled per lane: scol = ((lane&7) ^ (lane>>3))*8
//   - ds_read address swizzled the same way: col = ck ^ ((lr&7)<<3)
// SINGLE-buffered + __syncthreads.  DO NOT retry explicit double-buffer +
// counted vmcnt here: measured round 5 = 59->100us (VGPR 80->140, LDS
// 32->64KB, occupancy 26->10.5%, FETCH +45MB).  At ~2 blocks/CU the
// implicit wave-level overlap carries the pipeline; dbuf trades it away.
// MODE 0: fp32 C store.
// MODE 1: fused Q-rope epilogue -> bf16 (m = block row idx, n = in-tile row).
// MODE 2: plain bf16 store.
// MODE 3: fused K-rope epilogue -> bf16 (RK row == GEMM output row; only the
//         coefficients are gathered: mi=min(2y,127), ni=min(2x,127), freq at
//         (b,mi,ni)).  Eliminates the K0..K2 bf16 round-trip + rope_kv K-side.
//         sincosf in-epilogue (NOT table: round-2 falsified table here).
// lml = log2(level grid) for MODE 3 (6/5/4), ignored otherwise.
// ---------------------------------------------------------------------------
template <int MODE>
__device__ __forceinline__ void gemm_body(bf16_t* __restrict__ sA,
                                          bf16_t* __restrict__ sB,
                                          const bf16_t* __restrict__ A,
                                          const bf16_t* __restrict__ Bt,
                                          void* __restrict__ Cp,
                                          int row0, int col0,
                                          const float* __restrict__ freq,
                                          int lml) {
    const int tid  = threadIdx.x;
    const int wave = tid >> 6;
    const int lane = tid & 63;
    const int quad = lane >> 4;
    const int lr   = lane & 15;
    const int m_w  = (wave >> 1) * 64;
    const int n_w  = (wave & 1) * 64;

    // staging geometry: per wave 4 GLD16 per operand; instruction `it`
    // covers rows wave*32 + it*8 + (lane>>3), source col swizzled.
    const int r8  = lane >> 3;                 // row within 8-row stripe
    const int csw = ((lane & 7) ^ r8) * 8;     // pre-swizzled source column
    const bf16_t* gA = A  + (size_t)(row0 + wave * 32 + r8) * 512 + csw;
    const bf16_t* gB = Bt + (size_t)(col0 + wave * 32 + r8) * 512 + csw;
    bf16_t* dA = sA + wave * 2048;             // wave-uniform LDS bases
    bf16_t* dB = sB + wave * 2048;

    f32x4 acc[4][4];
#pragma unroll
    for (int i = 0; i < 4; ++i)
#pragma unroll
        for (int j = 0; j < 4; ++j)
#pragma unroll
            for (int r = 0; r < 4; ++r) acc[i][j][r] = 0.0f;

    const int sw = (lr & 7) << 3;              // read-side XOR (elements)

    for (int k0 = 0; k0 < 512; k0 += 64) {
#pragma unroll
        for (int it = 0; it < 4; ++it) {
            GLD16(dA + it * 512, gA + (size_t)(it * 8) * 512 + k0);
            GLD16(dB + it * 512, gB + (size_t)(it * 8) * 512 + k0);
        }
        __syncthreads();
#pragma unroll
        for (int kk = 0; kk < 64; kk += 32) {
            bf16x8 af[4], bfr[4];
#pragma unroll
            for (int i = 0; i < 4; ++i)
                af[i] = *(const bf16x8*)&sA[(m_w + i * 16 + lr) * 64 + ((kk + quad * 8) ^ sw)];
#pragma unroll
            for (int j = 0; j < 4; ++j)
                bfr[j] = *(const bf16x8*)&sB[(n_w + j * 16 + lr) * 64 + ((kk + quad * 8) ^ sw)];
#pragma unroll
            for (int i = 0; i < 4; ++i)
#pragma unroll
                for (int j = 0; j < 4; ++j)
                    acc[i][j] = __builtin_amdgcn_mfma_f32_16x16x32_bf16(
                        af[i], bfr[j], acc[i][j], 0, 0, 0);
        }
        __syncthreads();
    }

    if (MODE == 0) {
        float* C = (float*)Cp;
#pragma unroll
        for (int i = 0; i < 4; ++i) {
            const int rb = row0 + m_w + i * 16 + quad * 4;
#pragma unroll
            for (int j = 0; j < 4; ++j) {
                const int col = col0 + n_w + j * 16 + lr;
#pragma unroll
                for (int r = 0; r < 4; ++r)
                    C[(size_t)(rb + r) * 512 + col] = acc[i][j][r];
            }
        }
    } else if (MODE == 2) {
        bf16_t* C = (bf16_t*)Cp;
#pragma unroll
        for (int i = 0; i < 4; ++i) {
            const int rb = row0 + m_w + i * 16 + quad * 4;
#pragma unroll
            for (int j = 0; j < 4; ++j) {
                const int col = col0 + n_w + j * 16 + lr;
#pragma unroll
                for (int r = 0; r < 4; ++r)
                    C[(size_t)(rb + r) * 512 + col] = (bf16_t)acc[i][j][r];
            }
        }
    } else {
        // MODE 1 / MODE 3: fused freq-scale/offset + RoPE + bf16 store.
        // d = col & 63 = j*16 + lr (n_w in {0,64} drops out mod 64).
        // pair (d even, d odd) lives in lanes lr / lr^1 -> shfl_xor(x,1).
        // j=0: m-part p=lr>>1; j=1: m-part p=8+lr>>1; j=2/3: n-part same p.
        bf16_t* C = (bf16_t*)Cp;
        const float rad0 = expf(-LN1E4_OVER_32 * (float)(lr >> 1));        // p = lr>>1
        const float rad1 = expf(-LN1E4_OVER_32 * (float)(8 + (lr >> 1)));  // p = 8+lr>>1
        const int mbase = (row0 >> 7) & 127;   // MODE 1: m is block-constant
        const int mlm1  = (1 << lml) - 1;      // MODE 3: level grid mask
        float cs_m[2], sn_m[2];
        if (MODE == 1) {
            sincosf((float)mbase * rad0, &sn_m[0], &cs_m[0]);
            sincosf((float)mbase * rad1, &sn_m[1], &cs_m[1]);
        }
#pragma unroll
        for (int i = 0; i < 4; ++i) {
#pragma unroll
            for (int r = 0; r < 4; ++r) {
                const int rr = m_w + i * 16 + quad * 4 + r;
                const size_t pos = (size_t)row0 + rr;   // output row
                const float* fq;
                int an;
                if (MODE == 1) {
                    an = rr;                            // n index of 128-grid
                    fq = freq + pos * 128;
                } else {
                    const int rel = (int)pos;           // level-local row
                    const int bb  = rel >> (2 * lml);
                    const int y   = (rel >> lml) & mlm1;
                    const int x   = rel & mlm1;
                    const int am  = min(2 * y, 127);
                    an            = min(2 * x, 127);
                    fq = freq + ((size_t)(bb * 128 + am) * 128 + an) * 128;
                    sincosf((float)am * rad0, &sn_m[0], &cs_m[0]);
                    sincosf((float)am * rad1, &sn_m[1], &cs_m[1]);
                }
                float sn_n[2], cs_n[2];
                sincosf((float)an * rad0, &sn_n[0], &cs_n[0]);
                sincosf((float)an * rad1, &sn_n[1], &cs_n[1]);
#pragma unroll
                for (int j = 0; j < 4; ++j) {
                    const int col = col0 + n_w + j * 16 + lr;
                    const int d   = j * 16 + lr;
                    const float fs = fq[d], fo = fq[64 + d];
                    const float xp = acc[i][j][r] * fs + fo;
                    const float pr = __shfl_xor(xp, 1);
                    const float cs = (j < 2) ? cs_m[j & 1] : cs_n[j & 1];
                    const float sn = (j < 2) ? sn_m[j & 1] : sn_n[j & 1];
                    const float o  = (lr & 1) ? (sn * pr + cs * xp)
                                              : (cs * xp - sn * pr);
                    C[pos * 512 + col] = (bf16_t)o;
                }
            }
        }
    }
}

// all 7 projection GEMMs in one launch (1696 tile-blocks).
// K-GEMMs write roped RK directly (MODE 3); V-GEMMs write raw V (rope_kv
// does the V gather+rope).  XCD swizzle: same-A-row-tile blocks are
// 256/64/16 apart (== same XCD mod 8).
__global__ __launch_bounds__(256) void gemm_all(
    const bf16_t* __restrict__ Afm, const bf16_t* __restrict__ Ap0,
    const bf16_t* __restrict__ Ap1, const bf16_t* __restrict__ Ap2,
    const bf16_t* __restrict__ Tq, const bf16_t* __restrict__ Tk,
    const bf16_t* __restrict__ Tv,
    bf16_t* __restrict__ Qbf, bf16_t* __restrict__ RK,
    bf16_t* __restrict__ V0, bf16_t* __restrict__ V1,
    bf16_t* __restrict__ V2,
    const float* __restrict__ freq) {
    __shared__ __align__(16) bf16_t sA[128 * 64];
    __shared__ __align__(16) bf16_t sB[128 * 64];
    const int t = blockIdx.x;
    if (t < 1024) {
        gemm_body<1>(sA, sB, Afm, Tq, Qbf, (t & 255) * 128, (t >> 8) * 128, freq, 0);
    } else if (t < 1280) {
        const int u = t - 1024;
        gemm_body<3>(sA, sB, Ap0, Tk, RK + (size_t)L0_BASE * 512,
                     (u & 63) * 128, (u >> 6) * 128, freq, 6);
    } else if (t < 1536) {
        const int u = t - 1280;
        gemm_body<2>(sA, sB, Ap0, Tv, V0, (u & 63) * 128, (u >> 6) * 128, nullptr, 0);
    } else if (t < 1600) {
        const int u = t - 1536;
        gemm_body<3>(sA, sB, Ap1, Tk, RK + (size_t)L1_BASE * 512,
                     (u & 15) * 128, (u >> 4) * 128, freq, 5);
    } else if (t < 1664) {
        const int u = t - 1600;
        gemm_body<2>(sA, sB, Ap1, Tv, V1, (u & 15) * 128, (u >> 4) * 128, nullptr, 0);
    } else if (t < 1680) {
        const int u = t - 1664;
        gemm_body<3>(sA, sB, Ap2, Tk, RK + (size_t)L2_BASE * 512,
                     (u & 3) * 128, (u >> 2) * 128, freq, 4);
    } else {
        const int u = t - 1680;
        gemm_body<2>(sA, sB, Ap2, Tv, V2, (u & 3) * 128, (u >> 2) * 128, nullptr, 0);
    }
}

// output projection (fp32 out), same XCD swizzle
__global__ __launch_bounds__(256) void gemm_out(const bf16_t* __restrict__ A,
                                                const bf16_t* __restrict__ Bt,
                                                float* __restrict__ C) {
    __shared__ __align__(16) bf16_t sA[128 * 64];
    __shared__ __align__(16) bf16_t sB[128 * 64];
    const int t = blockIdx.x;
    gemm_body<0>(sA, sB, A, Bt, C, (t & 255) * 128, (t >> 8) * 128, nullptr, 0);
}

// ---------------------------------------------------------------------------
// Precompute roped V over each level's full grid (K now fused into the
// K-GEMM epilogue).  RV uses vy = min(y+pad, ml-1-pad) (valid-slot identity)
// with K's rope coefficients (reference quirk) -- a row GATHER, so it cannot
// fuse into the V-GEMM epilogue (one V row feeds many RV rows at borders).
// cos/sin from the precomputed table (measured faster than sincosf here).
// ---------------------------------------------------------------------------
__global__ __launch_bounds__(256) void rope_v(
    const bf16_t* __restrict__ V0, const bf16_t* __restrict__ V1,
    const bf16_t* __restrict__ V2,
    const float* __restrict__ freq, const float2* __restrict__ tab,
    bf16_t* __restrict__ RV) {
    const int pos = blockIdx.x;          // 0..10751
    int l, ml, pad, rel;
    if (pos < L1_BASE)      { l = 0; ml = 64; pad = 4; rel = pos; }
    else if (pos < L2_BASE) { l = 1; ml = 32; pad = 3; rel = pos - L1_BASE; }
    else                    { l = 2; ml = 16; pad = 2; rel = pos - L2_BASE; }
    const int b  = rel / (ml * ml);
    const int yx = rel - b * ml * ml;
    const int y  = yx / ml, x = yx % ml;
    const int vy = min(y + pad, ml - 1 - pad);
    const int vx = min(x + pad, ml - 1 - pad);
    const int mi = min(2 * y, 127), ni = min(2 * x, 127);
    const bf16_t* Vl = (l == 0) ? V0 : (l == 1) ? V1 : V2;

    const int tid = threadIdx.x;
    const int h  = tid >> 5;
    const int pr = tid & 31;
    const int p  = pr & 15;
    const int d0 = (pr < 16) ? (2 * p) : (32 + 2 * p);
    const float2 t = tab[((pr < 16) ? mi : ni) * 16 + p];
    const float cs = t.x, sn = t.y;

    const size_t fb   = ((size_t)(b * 128 + mi) * 128 + ni) * 128;
    const float fs0 = freq[fb + d0],      fs1 = freq[fb + d0 + 1];
    const float fo0 = freq[fb + 64 + d0], fo1 = freq[fb + 64 + d0 + 1];
    const size_t vidx = ((size_t)(b * ml + vy) * ml + vx) * 512 + h * 64 + d0;
    const size_t oidx = (size_t)pos * 512 + h * 64 + d0;
    const float x0 = (float)Vl[vidx] * fs0 + fo0;
    const float x1 = (float)Vl[vidx + 1] * fs1 + fo1;
    bf16x2 o;
    o[0] = (bf16_t)(cs * x0 - sn * x1);
    o[1] = (bf16_t)(sn * x0 + cs * x1);
    *(bf16x2*)(RV + oidx) = o;
}

// ---------------------------------------------------------------------------
// MFMA window attention (round-6 passing version, unchanged).
// ---------------------------------------------------------------------------
#define SKS 72    // sK row stride (bf16)
#define SPS 136   // sP row stride
#define SVS 134   // sVt row stride
__global__ __launch_bounds__(256, 4) void attn_mfma(
    const bf16_t* __restrict__ Qb,
    const bf16_t* __restrict__ RK, const bf16_t* __restrict__ RV,
    const float* __restrict__ pm0, const float* __restrict__ pm1, const float* __restrict__ pm2,
    const int* __restrict__ cy, const int* __restrict__ cx,
    bf16_t* __restrict__ att) {
    __shared__ __align__(16) bf16_t sK[NSLOT * SKS];   // sP (64*SPS) alias
    __shared__ __align__(16) bf16_t sVt[64 * SVS];     // transposed V
    __shared__ int   sOff[NSLOT];
    __shared__ float sValid[NSLOT];
    bf16_t* sP = sK;

    const int tid = threadIdx.x;
    const int h  = blockIdx.x & 7;
    const int wx = (blockIdx.x >> 3) & 15;
    const int wy = (blockIdx.x >> 7) & 15;
    const int b  = blockIdx.x >> 11;

    const int wave = tid >> 6, lane = tid & 63, quad = lane >> 4, lr = lane & 15;

    const int qrow = wave * 16 + lr;
    const int mq0 = wy * 8 + (qrow >> 3), nq0 = wx * 8 + (qrow & 7);
    const bf16_t* qp = Qb + ((size_t)((b * 128 + mq0) * 128 + nq0)) * 512 + h * 64 + quad * 8;
    const bf16x8 af0 = *(const bf16x8*)qp;
    const bf16x8 af1 = *(const bf16x8*)(qp + 32);

    if (tid < NSLOT) {
        const int j = tid;
        int off = 0;
        bool valid = false;
        if (j < NKEY) {
            const int c0y = cy[wy] >> 1, c0x = cx[wx] >> 1;
            const int c1y = (c0y + 8) >> 1, c1x = (c0x + 8) >> 1;
            const int c2y = (c1y + 6) >> 1, c2x = (c1x + 6) >> 1;
            int dy, dx, cry, crx, ml, pad, lbase;
            if (j < 64)       { dy = j >> 3;           dx = j & 7;  cry = c0y; crx = c0x; ml = 64; pad = 4; lbase = L0_BASE; }
            else if (j < 100) { int u = j - 64;  dy = u / 6;  dx = u % 6; cry = c1y; crx = c1x; ml = 32; pad = 3; lbase = L1_BASE; }
            else              { int u = j - 100; dy = u >> 2; dx = u & 3; cry = c2y; crx = c2x; ml = 16; pad = 2; lbase = L2_BASE; }
            const int ky = min(cry + dy, ml - 1) - pad;
            const int kx = min(crx + dx, ml - 1) - pad;
            if (ky >= 0 && kx >= 0) {
                const float* pm = (j < 64) ? pm0 : (j < 100) ? pm1 : pm2;
                valid = (pm[(b * ml + ky) * ml + kx] != 0.0f);
            }
            off = (lbase + (b * ml + max(ky, 0)) * ml + max(kx, 0)) * 512 + h * 64;
        }
        sOff[tid]   = off;
        sValid[tid] = valid ? 1.0f : 0.0f;
    }
    __syncthreads();

#pragma unroll
    for (int it = 0; it < 4; ++it) {
        const int idx = tid + it * 256;
        const int j = idx >> 3, c = (idx & 7) * 8;
        const int off = sOff[j];
        *(bf16x8*)&sK[j * SKS + c] = *(const bf16x8*)(RK + off + c);
        const bf16x8 v = *(const bf16x8*)(RV + off + c);
#pragma unroll
        for (int e = 0; e < 8; ++e) sVt[(c + e) * SVS + j] = v[e];
    }
    __syncthreads();

    f32x4 accs[8];
#pragma unroll
    for (int nt = 0; nt < 8; ++nt)
#pragma unroll
        for (int r = 0; r < 4; ++r) accs[nt][r] = 0.0f;
#pragma unroll
    for (int nt = 0; nt < 8; ++nt) {
        const bf16x8 b0 = *(const bf16x8*)&sK[(nt * 16 + lr) * SKS + quad * 8];
        const bf16x8 b1 = *(const bf16x8*)&sK[(nt * 16 + lr) * SKS + quad * 8 + 32];
        accs[nt] = __builtin_amdgcn_mfma_f32_16x16x32_bf16(af0, b0, accs[nt], 0, 0, 0);
        accs[nt] = __builtin_amdgcn_mfma_f32_16x16x32_bf16(af1, b1, accs[nt], 0, 0, 0);
    }

    float P[8][4];
#pragma unroll
    for (int nt = 0; nt < 8; ++nt) {
        const float vf = sValid[nt * 16 + lr];
#pragma unroll
        for (int r = 0; r < 4; ++r)
            P[nt][r] = (vf != 0.0f) ? accs[nt][r] * 0.125f : NEG_MAX;
    }

#pragma unroll
    for (int r = 0; r < 4; ++r) {
        float mx = P[0][r];
#pragma unroll
        for (int nt = 1; nt < 8; ++nt) mx = fmaxf(mx, P[nt][r]);
        for (int m = 1; m < 16; m <<= 1) mx = fmaxf(mx, __shfl_xor(mx, m));
        float sum = 0.0f;
#pragma unroll
        for (int nt = 0; nt < 8; ++nt) {
            const float e = __expf(P[nt][r] - mx);
            P[nt][r] = e;
            sum += e;
        }
        for (int m = 1; m < 16; m <<= 1) sum += __shfl_xor(sum, m);
        const float inv = 1.0f / sum;
#pragma unroll
        for (int nt = 0; nt < 8; ++nt) P[nt][r] *= inv;
    }

    __syncthreads();

#pragma unroll
    for (int nt = 0; nt < 8; ++nt)
#pragma unroll
        for (int r = 0; r < 4; ++r)
            sP[(wave * 16 + quad * 4 + r) * SPS + nt * 16 + lr] = (bf16_t)P[nt][r];
    __syncthreads();

    f32x4 acco[4];
#pragma unroll
    for (int nt = 0; nt < 4; ++nt)
#pragma unroll
        for (int r = 0; r < 4; ++r) acco[nt][r] = 0.0f;

    bf16x8 pa[4];
#pragma unroll
    for (int ks = 0; ks < 4; ++ks)
        pa[ks] = *(const bf16x8*)&sP[(wave * 16 + lr) * SPS + quad * 8 + ks * 32];
#pragma unroll
    for (int nt = 0; nt < 4; ++nt) {
#pragma unroll
        for (int ks = 0; ks < 4; ++ks) {
            const bf16x8 vb = *(const bf16x8*)&sVt[(nt * 16 + lr) * SVS + quad * 8 + ks * 32];
            acco[nt] = __builtin_amdgcn_mfma_f32_16x16x32_bf16(pa[ks], vb, acco[nt], 0, 0, 0);
        }
    }

#pragma unroll
    for (int nt = 0; nt < 4; ++nt) {
#pragma unroll
        for (int r = 0; r < 4; ++r) {
            const int q  = wave * 16 + quad * 4 + r;
            const int d  = nt * 16 + lr;
            const int mq = wy * 8 + (q >> 3), nq = wx * 8 + (q & 7);
            att[((size_t)((b * 128 + mq) * 128 + nq)) * 512 + h * 64 + d] = (bf16_t)acco[nt][r];
        }
    }
}

// ---------------------------------------------------------------------------
extern "C" void kernel_launch(void* const* d_in, const int* in_sizes, int n_in,
                              void* d_out, int out_size, void* d_ws, size_t ws_size,
                              hipStream_t stream) {
    const float* fmap = (const float*)d_in[0];
    const float* p0   = (const float*)d_in[1];
    const float* pm0  = (const float*)d_in[2];
    const float* p1   = (const float*)d_in[3];
    const float* pm1  = (const float*)d_in[4];
    const float* p2   = (const float*)d_in[5];
    const float* pm2  = (const float*)d_in[6];
    // d_in[7] = mask_q (all-true) -- not applied
    const float* freq = (const float*)d_in[8];
    const int*   cy   = (const int*)d_in[9];
    const int*   cx   = (const int*)d_in[10];
    const float* Wq   = (const float*)d_in[11];
    const float* Wk   = (const float*)d_in[12];
    const float* Wv   = (const float*)d_in[13];
    const float* Wo   = (const float*)d_in[14];
    float* out = (float*)d_out;

    // workspace carving (bytes, 256-aligned)
    char* base = (char*)d_ws;
    size_t off = 0;
    auto carve = [&](size_t bytes) {
        char* p = base + off; off += (bytes + 255) & ~(size_t)255; return p;
    };
    bf16_t* Afm  = (bf16_t*)carve(33554432);  // dead after gemm_all; attb aliases
    bf16_t* Ap0  = (bf16_t*)carve(8388608);
    bf16_t* Ap1  = (bf16_t*)carve(2097152);
    bf16_t* Ap2  = (bf16_t*)carve(524288);
    bf16_t* Tq   = (bf16_t*)carve(524288);
    bf16_t* Tk   = (bf16_t*)carve(524288);
    bf16_t* Tv   = (bf16_t*)carve(524288);
    bf16_t* To   = (bf16_t*)carve(524288);
    float2* rtab = (float2*)carve(16384);     // 128 pos x 16 p x (cos,sin)
    bf16_t* Qbf  = (bf16_t*)carve(33554432);  // roped Q (gemm_all MODE 1)
    bf16_t* V0   = (bf16_t*)carve(8388608);   // raw V projections
    bf16_t* V1   = (bf16_t*)carve(2097152);
    bf16_t* V2   = (bf16_t*)carve(524288);
    bf16_t* RK   = (bf16_t*)carve(11010048);  // roped K (gemm_all MODE 3)
    bf16_t* RV   = (bf16_t*)carve(11010048);  // roped V (rope_v)
    bf16_t* attb = Afm;                       // att bf16 aliases Afm (dead)

    // 1) fp32 -> bf16 conversions + weight transposes + rope table
    prep<<<CV_BLOCKS + 257, 256, 0, stream>>>(fmap, p0, p1, p2, Wq, Wk, Wv, Wo,
                                              Afm, Ap0, Ap1, Ap2, Tq, Tk, Tv, To,
                                              rtab);

    // 2) all 7 projection GEMMs; Q-rope fused (MODE 1), K-rope fused (MODE 3)
    gemm_all<<<1696, 256, 0, stream>>>(Afm, Ap0, Ap1, Ap2, Tq, Tk, Tv,
                                       Qbf, RK, V0, V1, V2, freq);

    // 3) roped V (bf16 -> bf16), table-driven cos/sin, row gather
    rope_v<<<NPOS_KV, 256, 0, stream>>>(V0, V1, V2, freq, rtab, RV);

    // 4) MFMA window attention -> bf16 att (into dead Afm region)
    attn_mfma<<<BB * MWIN * NWIN * NH, 256, 0, stream>>>(Qbf, RK, RV,
                                                         pm0, pm1, pm2, cy, cx, attb);

    // 5) output projection
    gemm_out<<<1024, 256, 0, stream>>>(attb, To, out);
}

// Round 8
// 293.399 us; speedup vs baseline: 1.2227x; 1.2227x over previous
//
#include <hip/hip_runtime.h>
#include <math.h>

// Problem constants (fixed by the reference)
#define BB 2
#define MM 128
#define NN 128
#define DE 512
#define NH 8
#define DH 64
#define SWIN 8
#define MWIN 16
#define NWIN 16
#define NKEY 116   // 64 + 36 + 16
#define NSLOT 128  // padded to 8 n-tiles of 16

#define NEG_MAX (-3.402823466e38f)
#define LN1E4_OVER_32 0.28782313662425575f   // ln(10000)/32 ; RAD[p] = exp(-p*this)

// level bases in "positions" for the concatenated RK/RV buffers
#define L0_BASE 0       // 2*64*64 = 8192 positions
#define L1_BASE 8192    // 2*32*32 = 2048
#define L2_BASE 10240   // 2*16*16 = 512
#define NPOS_KV 10752

typedef __bf16 bf16_t;
typedef bf16_t bf16x8 __attribute__((ext_vector_type(8)));
typedef bf16_t bf16x4 __attribute__((ext_vector_type(4)));
typedef bf16_t bf16x2 __attribute__((ext_vector_type(2)));
typedef float  f32x4  __attribute__((ext_vector_type(4)));

// async global->LDS, 16B per lane, dest = wave-uniform base + lane*16
#define GLD16(ldsdst, gsrc)                                                  \
    __builtin_amdgcn_global_load_lds(                                        \
        (const __attribute__((address_space(1))) unsigned int*)(gsrc),       \
        (__attribute__((address_space(3))) unsigned int*)(ldsdst), 16, 0, 0)

// ---------------------------------------------------------------------------
// prep: fused fp32->bf16 map conversion (blocks [0,21760)), weight
// transpose+convert (blocks [21760,22016): 4 weights x 64 tiles), and
// RoPE cos/sin table fill (block 22016): tab[pos*16+p] = (cos,sin)(pos*RAD[p])
// for pos 0..127, p 0..15.  Used by rope_kv only (NOT the GEMM epilogues --
// falsified twice: round 2 table-in-Q-epilogue -50%; round 7 K-rope fusion
// with per-row coefficient gathers: WRITE_SIZE 54->177MB, gemm_all 61->127us.
// Rope fusion into GEMM epilogues only works when coefficients are
// block-hoistable + contiguous per row (MODE 1 Q case).
// ---------------------------------------------------------------------------
#define CV_S0 16777216
#define CV_S1 20971520
#define CV_S2 22020096
#define CV_S3 22282240
#define CV_BLOCKS 21760
__global__ __launch_bounds__(256) void prep(
    const float* __restrict__ fmap, const float* __restrict__ p0,
    const float* __restrict__ p1, const float* __restrict__ p2,
    const float* __restrict__ Wq, const float* __restrict__ Wk,
    const float* __restrict__ Wv, const float* __restrict__ Wo,
    bf16_t* __restrict__ Afm, bf16_t* __restrict__ Ap0,
    bf16_t* __restrict__ Ap1, bf16_t* __restrict__ Ap2,
    bf16_t* __restrict__ Tq, bf16_t* __restrict__ Tk,
    bf16_t* __restrict__ Tv, bf16_t* __restrict__ To,
    float2* __restrict__ ropetab) {
    __shared__ float Ws[64][65];
    const int bid = blockIdx.x;
    const int tid = threadIdx.x;
    if (bid < CV_BLOCKS) {
        const int e = (bid * 256 + tid) * 4;
        const float* src; bf16_t* dst; int off;
        if (e < CV_S0)      { src = fmap; dst = Afm; off = e; }
        else if (e < CV_S1) { src = p0;   dst = Ap0; off = e - CV_S0; }
        else if (e < CV_S2) { src = p1;   dst = Ap1; off = e - CV_S1; }
        else if (e < CV_S3) { src = p2;   dst = Ap2; off = e - CV_S2; }
        else return;
        const float4 v = *(const float4*)(src + off);
        bf16x4 o;
        o[0] = (bf16_t)v.x; o[1] = (bf16_t)v.y; o[2] = (bf16_t)v.z; o[3] = (bf16_t)v.w;
        *(bf16x4*)(dst + off) = o;
    } else if (bid < CV_BLOCKS + 256) {
        const int idx = bid - CV_BLOCKS;     // 0..255
        const int w = idx >> 6, tile = idx & 63;
        const float* W = (w == 0) ? Wq : (w == 1) ? Wk : (w == 2) ? Wv : Wo;
        bf16_t*      T = (w == 0) ? Tq : (w == 1) ? Tk : (w == 2) ? Tv : To;
        const int tk0 = (tile >> 3) * 64;
        const int tn0 = (tile & 7) * 64;
#pragma unroll 4
        for (int i = 0; i < 16; ++i) {
            const int e = tid + i * 256;
            Ws[e >> 6][e & 63] = W[(tk0 + (e >> 6)) * 512 + tn0 + (e & 63)];
        }
        __syncthreads();
#pragma unroll 4
        for (int i = 0; i < 16; ++i) {
            const int e = tid + i * 256;
            const int ck = e & 63, rn = e >> 6;
            T[(size_t)(tn0 + rn) * 512 + tk0 + ck] = (bf16_t)Ws[ck][rn];
        }
    } else {
        // 2048 entries: tab[pos*16 + p] = (cos(pos*RAD[p]), sin(pos*RAD[p]))
#pragma unroll
        for (int i = 0; i < 8; ++i) {
            const int e = tid * 8 + i;       // 0..2047
            const int posn = e >> 4, p = e & 15;
            const float rad = expf(-LN1E4_OVER_32 * (float)p);
            float sn, cs;
            sincosf((float)posn * rad, &sn, &cs);
            ropetab[e] = make_float2(cs, sn);
        }
    }
}

// ---------------------------------------------------------------------------
// bf16 MFMA GEMM body (128x128 tile, 4 waves, 4x4 16x16x32 frags, BK=64).
// Staging: global_load_lds dwordx4 (async, no VGPR round-trip) into LINEAR
// LDS [128][64], with the XOR bank-swizzle applied on BOTH sides:
//   - SOURCE column pre-swizzled per lane: scol = ((lane&7) ^ (lane>>3))*8
//   - ds_read address swizzled the same way: col = ck ^ ((lr&7)<<3)
// SINGLE-buffered + __syncthreads.  DO NOT retry explicit double-buffer +
// counted vmcnt here: measured round 5 = 59->100us (VGPR 80->140, LDS
// 32->64KB, occupancy 26->10.5%, FETCH +45MB).  At ~2 blocks/CU the
// implicit wave-level overlap carries the pipeline; dbuf trades it away.
// MODE 0: fp32 C store. MODE 1: fused RoPE-Q epilogue -> bf16 (sincosf --
// measured faster than table loads here; coefficients block-hoistable).
// MODE 2: bf16.  (K-rope fusion = MODE 3 falsified in round 7, removed.)
// ---------------------------------------------------------------------------
template <int MODE>
__device__ __forceinline__ void gemm_body(bf16_t* __restrict__ sA,
                                          bf16_t* __restrict__ sB,
                                          const bf16_t* __restrict__ A,
                                          const bf16_t* __restrict__ Bt,
                                          void* __restrict__ Cp,
                                          int row0, int col0,
                                          const float* __restrict__ freq) {
    const int tid  = threadIdx.x;
    const int wave = tid >> 6;
    const int lane = tid & 63;
    const int quad = lane >> 4;
    const int lr   = lane & 15;
    const int m_w  = (wave >> 1) * 64;
    const int n_w  = (wave & 1) * 64;

    // staging geometry: per wave 4 GLD16 per operand; instruction `it`
    // covers rows wave*32 + it*8 + (lane>>3), source col swizzled.
    const int r8  = lane >> 3;                 // row within 8-row stripe
    const int csw = ((lane & 7) ^ r8) * 8;     // pre-swizzled source column
    const bf16_t* gA = A  + (size_t)(row0 + wave * 32 + r8) * 512 + csw;
    const bf16_t* gB = Bt + (size_t)(col0 + wave * 32 + r8) * 512 + csw;
    bf16_t* dA = sA + wave * 2048;             // wave-uniform LDS bases
    bf16_t* dB = sB + wave * 2048;

    f32x4 acc[4][4];
#pragma unroll
    for (int i = 0; i < 4; ++i)
#pragma unroll
        for (int j = 0; j < 4; ++j)
#pragma unroll
            for (int r = 0; r < 4; ++r) acc[i][j][r] = 0.0f;

    const int sw = (lr & 7) << 3;              // read-side XOR (elements)

    for (int k0 = 0; k0 < 512; k0 += 64) {
#pragma unroll
        for (int it = 0; it < 4; ++it) {
            GLD16(dA + it * 512, gA + (size_t)(it * 8) * 512 + k0);
            GLD16(dB + it * 512, gB + (size_t)(it * 8) * 512 + k0);
        }
        __syncthreads();
#pragma unroll
        for (int kk = 0; kk < 64; kk += 32) {
            bf16x8 af[4], bfr[4];
#pragma unroll
            for (int i = 0; i < 4; ++i)
                af[i] = *(const bf16x8*)&sA[(m_w + i * 16 + lr) * 64 + ((kk + quad * 8) ^ sw)];
#pragma unroll
            for (int j = 0; j < 4; ++j)
                bfr[j] = *(const bf16x8*)&sB[(n_w + j * 16 + lr) * 64 + ((kk + quad * 8) ^ sw)];
#pragma unroll
            for (int i = 0; i < 4; ++i)
#pragma unroll
                for (int j = 0; j < 4; ++j)
                    acc[i][j] = __builtin_amdgcn_mfma_f32_16x16x32_bf16(
                        af[i], bfr[j], acc[i][j], 0, 0, 0);
        }
        __syncthreads();
    }

    if (MODE == 0) {
        float* C = (float*)Cp;
#pragma unroll
        for (int i = 0; i < 4; ++i) {
            const int rb = row0 + m_w + i * 16 + quad * 4;
#pragma unroll
            for (int j = 0; j < 4; ++j) {
                const int col = col0 + n_w + j * 16 + lr;
#pragma unroll
                for (int r = 0; r < 4; ++r)
                    C[(size_t)(rb + r) * 512 + col] = acc[i][j][r];
            }
        }
    } else if (MODE == 2) {
        bf16_t* C = (bf16_t*)Cp;
#pragma unroll
        for (int i = 0; i < 4; ++i) {
            const int rb = row0 + m_w + i * 16 + quad * 4;
#pragma unroll
            for (int j = 0; j < 4; ++j) {
                const int col = col0 + n_w + j * 16 + lr;
#pragma unroll
                for (int r = 0; r < 4; ++r)
                    C[(size_t)(rb + r) * 512 + col] = (bf16_t)acc[i][j][r];
            }
        }
    } else {
        // MODE 1: fused freq-scale/offset + RoPE + bf16 store.
        // d = col & 63 = j*16 + lr (n_w in {0,64} drops out mod 64).
        // m = row0>>7 & 127 block-constant; n = in-block row rr.
        // pair (d even, d odd) lives in lanes lr / lr^1 -> shfl_xor(x,1).
        bf16_t* C = (bf16_t*)Cp;
        const int mbase = (row0 >> 7) & 127;
        const float rad0 = expf(-LN1E4_OVER_32 * (float)(lr >> 1));        // p = lr>>1
        const float rad1 = expf(-LN1E4_OVER_32 * (float)(8 + (lr >> 1)));  // p = 8+lr>>1
        float cs_m[2], sn_m[2];
        sincosf((float)mbase * rad0, &sn_m[0], &cs_m[0]);
        sincosf((float)mbase * rad1, &sn_m[1], &cs_m[1]);
#pragma unroll
        for (int i = 0; i < 4; ++i) {
#pragma unroll
            for (int r = 0; r < 4; ++r) {
                const int rr = m_w + i * 16 + quad * 4 + r;    // n index
                const size_t pos = (size_t)row0 + rr;
                float sn_n[2], cs_n[2];
                sincosf((float)rr * rad0, &sn_n[0], &cs_n[0]);
                sincosf((float)rr * rad1, &sn_n[1], &cs_n[1]);
                const float* fq = freq + pos * 128;
#pragma unroll
                for (int j = 0; j < 4; ++j) {
                    const int col = col0 + n_w + j * 16 + lr;
                    const int d   = j * 16 + lr;
                    const float fs = fq[d], fo = fq[64 + d];
                    const float xp = acc[i][j][r] * fs + fo;
                    const float pr = __shfl_xor(xp, 1);
                    const float cs = (j < 2) ? cs_m[j & 1] : cs_n[j & 1];
                    const float sn = (j < 2) ? sn_m[j & 1] : sn_n[j & 1];
                    const float o  = (lr & 1) ? (sn * pr + cs * xp)
                                              : (cs * xp - sn * pr);
                    C[pos * 512 + col] = (bf16_t)o;
                }
            }
        }
    }
}

// all 7 projection GEMMs in one launch (1696 tile-blocks).
// XCD swizzle: same-A-row-tile blocks are 256/64/16 apart (== same XCD mod 8).
__global__ __launch_bounds__(256) void gemm_all(
    const bf16_t* __restrict__ Afm, const bf16_t* __restrict__ Ap0,
    const bf16_t* __restrict__ Ap1, const bf16_t* __restrict__ Ap2,
    const bf16_t* __restrict__ Tq, const bf16_t* __restrict__ Tk,
    const bf16_t* __restrict__ Tv,
    bf16_t* __restrict__ Qbf,
    bf16_t* __restrict__ K0, bf16_t* __restrict__ V0,
    bf16_t* __restrict__ K1, bf16_t* __restrict__ V1,
    bf16_t* __restrict__ K2, bf16_t* __restrict__ V2,
    const float* __restrict__ freq) {
    __shared__ __align__(16) bf16_t sA[128 * 64];
    __shared__ __align__(16) bf16_t sB[128 * 64];
    const int t = blockIdx.x;
    if (t < 1024) {
        gemm_body<1>(sA, sB, Afm, Tq, Qbf, (t & 255) * 128, (t >> 8) * 128, freq);
    } else if (t < 1280) {
        const int u = t - 1024;
        gemm_body<2>(sA, sB, Ap0, Tk, K0, (u & 63) * 128, (u >> 6) * 128, nullptr);
    } else if (t < 1536) {
        const int u = t - 1280;
        gemm_body<2>(sA, sB, Ap0, Tv, V0, (u & 63) * 128, (u >> 6) * 128, nullptr);
    } else if (t < 1600) {
        const int u = t - 1536;
        gemm_body<2>(sA, sB, Ap1, Tk, K1, (u & 15) * 128, (u >> 4) * 128, nullptr);
    } else if (t < 1664) {
        const int u = t - 1600;
        gemm_body<2>(sA, sB, Ap1, Tv, V1, (u & 15) * 128, (u >> 4) * 128, nullptr);
    } else if (t < 1680) {
        const int u = t - 1664;
        gemm_body<2>(sA, sB, Ap2, Tk, K2, (u & 3) * 128, (u >> 2) * 128, nullptr);
    } else {
        const int u = t - 1680;
        gemm_body<2>(sA, sB, Ap2, Tv, V2, (u & 3) * 128, (u >> 2) * 128, nullptr);
    }
}

// output projection (fp32 out), same XCD swizzle
__global__ __launch_bounds__(256) void gemm_out(const bf16_t* __restrict__ A,
                                                const bf16_t* __restrict__ Bt,
                                                float* __restrict__ C) {
    __shared__ __align__(16) bf16_t sA[128 * 64];
    __shared__ __align__(16) bf16_t sB[128 * 64];
    const int t = blockIdx.x;
    gemm_body<0>(sA, sB, A, Bt, C, (t & 255) * 128, (t >> 8) * 128, nullptr);
}

// ---------------------------------------------------------------------------
// Precompute roped K and V (bf16 in, bf16 out) over each level's full grid.
// RV uses vy = min(y+pad, ml-1-pad) (valid-slot identity) with K's rope
// coefficients (reference quirk).  cos/sin from the precomputed table
// (measured faster than sincosf here in round 2).
// VECTORIZED (G13): 4 rows/block, 8 bf16 per thread (16B/lane loads+stores
// on K, V, RK, RV) instead of bf16x2 (4B/lane).  An 8-elem block never
// straddles the m/n coefficient split at d=32, so all 4 pairs share the
// same tab row (mi or ni).
// ---------------------------------------------------------------------------
__global__ __launch_bounds__(256) void rope_kv(
    const bf16_t* __restrict__ K0, const bf16_t* __restrict__ K1, const bf16_t* __restrict__ K2,
    const bf16_t* __restrict__ V0, const bf16_t* __restrict__ V1, const bf16_t* __restrict__ V2,
    const float* __restrict__ freq, const float2* __restrict__ tab,
    bf16_t* __restrict__ RK, bf16_t* __restrict__ RV) {
    const int tid = threadIdx.x;
    const int pos = blockIdx.x * 4 + (tid >> 6);   // 0..10751
    int l, ml, pad, rel;
    if (pos < L1_BASE)      { l = 0; ml = 64; pad = 4; rel = pos; }
    else if (pos < L2_BASE) { l = 1; ml = 32; pad = 3; rel = pos - L1_BASE; }
    else                    { l = 2; ml = 16; pad = 2; rel = pos - L2_BASE; }
    const int b  = rel / (ml * ml);
    const int yx = rel - b * ml * ml;
    const int y  = yx / ml, x = yx % ml;
    const int vy = min(y + pad, ml - 1 - pad);
    const int vx = min(x + pad, ml - 1 - pad);
    const int mi = min(2 * y, 127), ni = min(2 * x, 127);
    const bf16_t* Kl = (l == 0) ? K0 : (l == 1) ? K1 : K2;
    const bf16_t* Vl = (l == 0) ? V0 : (l == 1) ? V1 : V2;

    const int e  = (tid & 63) * 8;        // 0..504: h*64 + d0
    const int d0 = e & 63;                // within-head d offset (8-aligned)
    const bool mpart = (d0 < 32);
    const int p0 = mpart ? (d0 >> 1) : ((d0 - 32) >> 1);
    const float2* tp = tab + (mpart ? mi : ni) * 16 + p0;   // 4 coeff pairs

    const float* fq = freq + ((size_t)(b * 128 + mi) * 128 + ni) * 128;
    const size_t kbase = ((size_t)(b * ml + y)  * ml + x)  * 512 + e;
    const size_t vbase = ((size_t)(b * ml + vy) * ml + vx) * 512 + e;
    const size_t obase = (size_t)pos * 512 + e;

    const bf16x8 kv = *(const bf16x8*)(Kl + kbase);
    const bf16x8 vv = *(const bf16x8*)(Vl + vbase);
    bf16x8 ok, ov;
#pragma unroll
    for (int k = 0; k < 4; ++k) {
        const float2 t2 = tp[k];
        const int d = d0 + 2 * k;
        const float fs0 = fq[d],      fs1 = fq[d + 1];
        const float fo0 = fq[64 + d], fo1 = fq[64 + d + 1];
        {
            const float x0 = (float)kv[2 * k] * fs0 + fo0;
            const float x1 = (float)kv[2 * k + 1] * fs1 + fo1;
            ok[2 * k]     = (bf16_t)(t2.x * x0 - t2.y * x1);
            ok[2 * k + 1] = (bf16_t)(t2.y * x0 + t2.x * x1);
        }
        {
            const float x0 = (float)vv[2 * k] * fs0 + fo0;
            const float x1 = (float)vv[2 * k + 1] * fs1 + fo1;
            ov[2 * k]     = (bf16_t)(t2.x * x0 - t2.y * x1);
            ov[2 * k + 1] = (bf16_t)(t2.y * x0 + t2.x * x1);
        }
    }
    *(bf16x8*)(RK + obase) = ok;
    *(bf16x8*)(RV + obase) = ov;
}

// ---------------------------------------------------------------------------
// MFMA window attention (round-6 passing version, unchanged).
// ---------------------------------------------------------------------------
#define SKS 72    // sK row stride (bf16)
#define SPS 136   // sP row stride
#define SVS 134   // sVt row stride
__global__ __launch_bounds__(256, 4) void attn_mfma(
    const bf16_t* __restrict__ Qb,
    const bf16_t* __restrict__ RK, const bf16_t* __restrict__ RV,
    const float* __restrict__ pm0, const float* __restrict__ pm1, const float* __restrict__ pm2,
    const int* __restrict__ cy, const int* __restrict__ cx,
    bf16_t* __restrict__ att) {
    __shared__ __align__(16) bf16_t sK[NSLOT * SKS];   // sP (64*SPS) alias
    __shared__ __align__(16) bf16_t sVt[64 * SVS];     // transposed V
    __shared__ int   sOff[NSLOT];
    __shared__ float sValid[NSLOT];
    bf16_t* sP = sK;

    const int tid = threadIdx.x;
    const int h  = blockIdx.x & 7;
    const int wx = (blockIdx.x >> 3) & 15;
    const int wy = (blockIdx.x >> 7) & 15;
    const int b  = blockIdx.x >> 11;

    const int wave = tid >> 6, lane = tid & 63, quad = lane >> 4, lr = lane & 15;

    const int qrow = wave * 16 + lr;
    const int mq0 = wy * 8 + (qrow >> 3), nq0 = wx * 8 + (qrow & 7);
    const bf16_t* qp = Qb + ((size_t)((b * 128 + mq0) * 128 + nq0)) * 512 + h * 64 + quad * 8;
    const bf16x8 af0 = *(const bf16x8*)qp;
    const bf16x8 af1 = *(const bf16x8*)(qp + 32);

    if (tid < NSLOT) {
        const int j = tid;
        int off = 0;
        bool valid = false;
        if (j < NKEY) {
            const int c0y = cy[wy] >> 1, c0x = cx[wx] >> 1;
            const int c1y = (c0y + 8) >> 1, c1x = (c0x + 8) >> 1;
            const int c2y = (c1y + 6) >> 1, c2x = (c1x + 6) >> 1;
            int dy, dx, cry, crx, ml, pad, lbase;
            if (j < 64)       { dy = j >> 3;           dx = j & 7;  cry = c0y; crx = c0x; ml = 64; pad = 4; lbase = L0_BASE; }
            else if (j < 100) { int u = j - 64;  dy = u / 6;  dx = u % 6; cry = c1y; crx = c1x; ml = 32; pad = 3; lbase = L1_BASE; }
            else              { int u = j - 100; dy = u >> 2; dx = u & 3; cry = c2y; crx = c2x; ml = 16; pad = 2; lbase = L2_BASE; }
            const int ky = min(cry + dy, ml - 1) - pad;
            const int kx = min(crx + dx, ml - 1) - pad;
            if (ky >= 0 && kx >= 0) {
                const float* pm = (j < 64) ? pm0 : (j < 100) ? pm1 : pm2;
                valid = (pm[(b * ml + ky) * ml + kx] != 0.0f);
            }
            off = (lbase + (b * ml + max(ky, 0)) * ml + max(kx, 0)) * 512 + h * 64;
        }
        sOff[tid]   = off;
        sValid[tid] = valid ? 1.0f : 0.0f;
    }
    __syncthreads();

#pragma unroll
    for (int it = 0; it < 4; ++it) {
        const int idx = tid + it * 256;
        const int j = idx >> 3, c = (idx & 7) * 8;
        const int off = sOff[j];
        *(bf16x8*)&sK[j * SKS + c] = *(const bf16x8*)(RK + off + c);
        const bf16x8 v = *(const bf16x8*)(RV + off + c);
#pragma unroll
        for (int e = 0; e < 8; ++e) sVt[(c + e) * SVS + j] = v[e];
    }
    __syncthreads();

    f32x4 accs[8];
#pragma unroll
    for (int nt = 0; nt < 8; ++nt)
#pragma unroll
        for (int r = 0; r < 4; ++r) accs[nt][r] = 0.0f;
#pragma unroll
    for (int nt = 0; nt < 8; ++nt) {
        const bf16x8 b0 = *(const bf16x8*)&sK[(nt * 16 + lr) * SKS + quad * 8];
        const bf16x8 b1 = *(const bf16x8*)&sK[(nt * 16 + lr) * SKS + quad * 8 + 32];
        accs[nt] = __builtin_amdgcn_mfma_f32_16x16x32_bf16(af0, b0, accs[nt], 0, 0, 0);
        accs[nt] = __builtin_amdgcn_mfma_f32_16x16x32_bf16(af1, b1, accs[nt], 0, 0, 0);
    }

    float P[8][4];
#pragma unroll
    for (int nt = 0; nt < 8; ++nt) {
        const float vf = sValid[nt * 16 + lr];
#pragma unroll
        for (int r = 0; r < 4; ++r)
            P[nt][r] = (vf != 0.0f) ? accs[nt][r] * 0.125f : NEG_MAX;
    }

#pragma unroll
    for (int r = 0; r < 4; ++r) {
        float mx = P[0][r];
#pragma unroll
        for (int nt = 1; nt < 8; ++nt) mx = fmaxf(mx, P[nt][r]);
        for (int m = 1; m < 16; m <<= 1) mx = fmaxf(mx, __shfl_xor(mx, m));
        float sum = 0.0f;
#pragma unroll
        for (int nt = 0; nt < 8; ++nt) {
            const float e = __expf(P[nt][r] - mx);
            P[nt][r] = e;
            sum += e;
        }
        for (int m = 1; m < 16; m <<= 1) sum += __shfl_xor(sum, m);
        const float inv = 1.0f / sum;
#pragma unroll
        for (int nt = 0; nt < 8; ++nt) P[nt][r] *= inv;
    }

    __syncthreads();

#pragma unroll
    for (int nt = 0; nt < 8; ++nt)
#pragma unroll
        for (int r = 0; r < 4; ++r)
            sP[(wave * 16 + quad * 4 + r) * SPS + nt * 16 + lr] = (bf16_t)P[nt][r];
    __syncthreads();

    f32x4 acco[4];
#pragma unroll
    for (int nt = 0; nt < 4; ++nt)
#pragma unroll
        for (int r = 0; r < 4; ++r) acco[nt][r] = 0.0f;

    bf16x8 pa[4];
#pragma unroll
    for (int ks = 0; ks < 4; ++ks)
        pa[ks] = *(const bf16x8*)&sP[(wave * 16 + lr) * SPS + quad * 8 + ks * 32];
#pragma unroll
    for (int nt = 0; nt < 4; ++nt) {
#pragma unroll
        for (int ks = 0; ks < 4; ++ks) {
            const bf16x8 vb = *(const bf16x8*)&sVt[(nt * 16 + lr) * SVS + quad * 8 + ks * 32];
            acco[nt] = __builtin_amdgcn_mfma_f32_16x16x32_bf16(pa[ks], vb, acco[nt], 0, 0, 0);
        }
    }

#pragma unroll
    for (int nt = 0; nt < 4; ++nt) {
#pragma unroll
        for (int r = 0; r < 4; ++r) {
            const int q  = wave * 16 + quad * 4 + r;
            const int d  = nt * 16 + lr;
            const int mq = wy * 8 + (q >> 3), nq = wx * 8 + (q & 7);
            att[((size_t)((b * 128 + mq) * 128 + nq)) * 512 + h * 64 + d] = (bf16_t)acco[nt][r];
        }
    }
}

// ---------------------------------------------------------------------------
extern "C" void kernel_launch(void* const* d_in, const int* in_sizes, int n_in,
                              void* d_out, int out_size, void* d_ws, size_t ws_size,
                              hipStream_t stream) {
    const float* fmap = (const float*)d_in[0];
    const float* p0   = (const float*)d_in[1];
    const float* pm0  = (const float*)d_in[2];
    const float* p1   = (const float*)d_in[3];
    const float* pm1  = (const float*)d_in[4];
    const float* p2   = (const float*)d_in[5];
    const float* pm2  = (const float*)d_in[6];
    // d_in[7] = mask_q (all-true) -- not applied
    const float* freq = (const float*)d_in[8];
    const int*   cy   = (const int*)d_in[9];
    const int*   cx   = (const int*)d_in[10];
    const float* Wq   = (const float*)d_in[11];
    const float* Wk   = (const float*)d_in[12];
    const float* Wv   = (const float*)d_in[13];
    const float* Wo   = (const float*)d_in[14];
    float* out = (float*)d_out;

    // workspace carving (bytes, 256-aligned)
    char* base = (char*)d_ws;
    size_t off = 0;
    auto carve = [&](size_t bytes) {
        char* p = base + off; off += (bytes + 255) & ~(size_t)255; return p;
    };
    bf16_t* Afm  = (bf16_t*)carve(33554432);  // dead after gemm_all; attb aliases
    bf16_t* Ap0  = (bf16_t*)carve(8388608);
    bf16_t* Ap1  = (bf16_t*)carve(2097152);
    bf16_t* Ap2  = (bf16_t*)carve(524288);
    bf16_t* Tq   = (bf16_t*)carve(524288);
    bf16_t* Tk   = (bf16_t*)carve(524288);
    bf16_t* Tv   = (bf16_t*)carve(524288);
    bf16_t* To   = (bf16_t*)carve(524288);
    float2* rtab = (float2*)carve(16384);     // 128 pos x 16 p x (cos,sin)
    bf16_t* Qbf  = (bf16_t*)carve(33554432);  // roped Q (written by gemm_all MODE 1)
    bf16_t* K0   = (bf16_t*)carve(8388608);   // bf16 projections
    bf16_t* V0   = (bf16_t*)carve(8388608);
    bf16_t* K1   = (bf16_t*)carve(2097152);
    bf16_t* V1   = (bf16_t*)carve(2097152);
    bf16_t* K2   = (bf16_t*)carve(524288);
    bf16_t* V2   = (bf16_t*)carve(524288);
    bf16_t* RK   = (bf16_t*)carve(11010048); // 10752*512 bf16
    bf16_t* RV   = (bf16_t*)carve(11010048);
    bf16_t* attb = Afm;                       // att bf16 aliases Afm (dead)

    // 1) fp32 -> bf16 conversions + weight transposes + rope table
    prep<<<CV_BLOCKS + 257, 256, 0, stream>>>(fmap, p0, p1, p2, Wq, Wk, Wv, Wo,
                                              Afm, Ap0, Ap1, Ap2, Tq, Tk, Tv, To,
                                              rtab);

    // 2) all 7 projection GEMMs; Q gets fused freq+RoPE epilogue -> Qbf
    gemm_all<<<1696, 256, 0, stream>>>(Afm, Ap0, Ap1, Ap2, Tq, Tk, Tv,
                                       Qbf, K0, V0, K1, V1, K2, V2, freq);

    // 3) roped K/V (bf16 -> bf16), table cos/sin, 16B/lane vectorized
    rope_kv<<<NPOS_KV / 4, 256, 0, stream>>>(K0, K1, K2, V0, V1, V2, freq, rtab,
                                             RK, RV);

    // 4) MFMA window attention -> bf16 att (into dead Afm region)
    attn_mfma<<<BB * MWIN * NWIN * NH, 256, 0, stream>>>(Qbf, RK, RV,
                                                         pm0, pm1, pm2, cy, cx, attb);

    // 5) output projection
    gemm_out<<<1024, 256, 0, stream>>>(attb, To, out);
}